// Round 6
// baseline (693.280 us; speedup 1.0000x reference)
//
#include <hip/hip_runtime.h>

// LSTMPricePredictor: B=4096, T=512, IN=1, H=50, 2 layers + FC(50->1)
// R22 = R17 (best, 362us) re-parameterized to NB=8, 512 blocks, 2 blocks/CU.
//   Post-mortems R18/R19/R21: all within-barrier-domain overlap attempts
//   failed; step = SUM of lockstep bursts (LDS 416 + MFMA 466 + trans/VALU
//   730 + skew 150 = 1760cyc = measured). The barrier locksteps all waves.
//   R22 breaks lockstep with TWO independent barrier domains per CU:
//   batch columns are independent streams, so 16-batch groups split into
//   two NB=8 blocks. When block A stalls (barrier/LDS), block B fills the
//   VALU/MFMA pipes. CU work doubles (dead cols) but pipes overlap:
//   pipe-bound wall = 512 x max(VALU ~1270, MFMA ~760, LDS ~830) ~ 272us.
// Carried from R17 (byte-identical step body): x rank-1 via C-operand,
//   bias as MFMA C-operand, unconditional h stores into dead k=50/51
//   slots, 2-rcp cell_update with c pre-scaled by 2*log2e, raw v_exp_f32.
//   Junk cols 8-15 are column-isolated through MFMA (per-col sums) and
//   stay finite (EW of finite input is in [-1,1]).

typedef _Float16 half8 __attribute__((ext_vector_type(8)));
typedef float    f32x4 __attribute__((ext_vector_type(4)));

#define TT    512
#define HID   50
#define NB    8          // batch rows per block (2 blocks/CU)
#define XST   9          // xs row stride in floats (8 cols + 1 pad)
#define LOG2E 1.44269504f

// Weight A-fragment: lane's 8 fp16 for K-chunk `chunk`, pre-scaled by the
// gate's exp2 factor. Row m -> gate = m&3, cell = 4*wv + (m>>2).
// W is (200 x 50): element [gate*50+cell][k]. Rows with cell >= 50 and
// k-slots >= 50 are zero (dead lanes multiply by zero).
__device__ __forceinline__ float4 make_wfrag(const float* W, int gate, int cell,
                                             int chunk, int quad, float scale) {
    half8 hv = {};
    #pragma unroll
    for (int j = 0; j < 8; ++j) {
        const int k = 32 * chunk + 8 * quad + j;
        float v = 0.0f;
        if (cell < HID && k < HID) v = W[(gate * HID + cell) * HID + k] * scale;
        hv[j] = (_Float16)v;
    }
    return __builtin_bit_cast(float4, hv);
}

// Shared-rcp LSTM cell update on pre-scaled gates, RAW hardware exp2.
//   a0 = -i*log2e, a1 = -f*log2e, a2 = 2g*log2e, a3 = -o*log2e.
// ct = c * 2*log2e carried across steps. Common denominator:
//   ct' = [ct*p + K(eg-1)*q] / (p*q),  p=(1+ei)(1+eg), q=(1+ef), K=2log2e.
// Worst-case p*q <= 2^82 -- no overflow. Dead lanes: all-zero gates give
// ei=ef=eg=eo=1 -> ct stays 0, h = 0 exactly.
__device__ __forceinline__ float cell_update(const f32x4 a, float& ct) {
    const float K  = 2.0f * LOG2E;
    const float ei = __builtin_amdgcn_exp2f(a[0]);   // e^{-i}
    const float ef = __builtin_amdgcn_exp2f(a[1]);   // e^{-f}
    const float eg = __builtin_amdgcn_exp2f(a[2]);   // e^{2g}
    const float eo = __builtin_amdgcn_exp2f(a[3]);   // e^{-o}
    const float p  = (1.0f + ei) * (1.0f + eg);
    const float q  = 1.0f + ef;
    const float t1 = __builtin_fmaf(eg, K, -K);                  // K*(eg-1)
    const float num = __builtin_fmaf(ct, p, t1 * q);
    ct = num * __builtin_amdgcn_rcpf(p * q);                     // K*c'
    const float ec = __builtin_amdgcn_exp2f(ct);                 // e^{2c'}
    return (ec - 1.0f) *
        __builtin_amdgcn_rcpf((1.0f + eo) * (ec + 1.0f));        // sig(o)*tanh(c')
}

#define PIN(f) asm volatile("" : "+v"(f.x), "+v"(f.y), "+v"(f.z), "+v"(f.w));
#define MFMA(af, b, c) __builtin_amdgcn_mfma_f32_16x16x32_f16(__builtin_bit_cast(half8, (af)), (b), (c), 0, 0, 0)

extern "C" __global__ __launch_bounds__(832, 4)
void lstm2_mfma_kernel(const float* __restrict__ x,
                       const float* __restrict__ W_ih0, const float* __restrict__ W_hh0,
                       const float* __restrict__ b_ih0, const float* __restrict__ b_hh0,
                       const float* __restrict__ W_ih1, const float* __restrict__ W_hh1,
                       const float* __restrict__ b_ih1, const float* __restrict__ b_hh1,
                       const float* __restrict__ fc_w, const float* __restrict__ fc_b,
                       float* __restrict__ out)
{
    // h-state in B-fragment layout: element (k, n) at (k>>5)*512 +
    // (((k&31)>>3)*16 + n)*8 + (k&7). k<50 = h; k=50/51 slots are dead
    // (zero A-weights) and absorb the cellD=50/51 stores (h=0 anyway).
    // Cols 0..7 real batch; cols 8..15 junk (column-isolated, finite).
    __shared__ _Float16 H0[2][1024];
    __shared__ _Float16 H1[2][1024];
    __shared__ float    xs[TT * XST];     // x staged fp32, [u*XST + row]
    __shared__ float    hfin[52 * 16];    // fp32 h1^(TT) for the FC epilogue

    const int tid  = threadIdx.x;
    const int lane = tid & 63;
    const int wv   = tid >> 6;            // wave 0..12 = gate-row tile
    const int b0   = blockIdx.x * NB;

    for (int i = tid; i < 1024; i += 832) {
        H0[0][i] = (_Float16)0.f; H0[1][i] = (_Float16)0.f;
        H1[0][i] = (_Float16)0.f; H1[1][i] = (_Float16)0.f;
    }
    // One-shot x stage: coalesced global read, stride-9 LDS write.
    for (int i = tid; i < NB * TT; i += 832) {
        const int row = i >> 9;           // batch row 0..7
        const int uu  = i & (TT - 1);     // timestep
        xs[uu * XST + row] = x[(size_t)(b0 + row) * TT + uu];
    }

    const int quad = lane >> 4;
    const int col  = lane & 15;           // batch column (8..15 junk)
    const int xcol = col & 7;             // x read column (junk cols alias real)
    const int mrow = lane & 15;           // A-row within tile
    const int gateA = mrow & 3;
    const int cellA = 4 * wv + (mrow >> 2);
    const float scA = (gateA == 2) ? 2.0f * LOG2E : -LOG2E;

    // ---- A-fragments (weights, exp2-prescaled), loaded once, pinned ----
    float4 A0c0 = make_wfrag(W_hh0, gateA, cellA, 0, quad, scA);
    float4 A0c1 = make_wfrag(W_hh0, gateA, cellA, 1, quad, scA);
    float4 Aic0 = make_wfrag(W_ih1, gateA, cellA, 0, quad, scA);
    float4 Aic1 = make_wfrag(W_ih1, gateA, cellA, 1, quad, scA);
    float4 Ahc0 = make_wfrag(W_hh1, gateA, cellA, 0, quad, scA);
    float4 Ahc1 = make_wfrag(W_hh1, gateA, cellA, 1, quad, scA);
    PIN(A0c0) PIN(A0c1) PIN(Aic0) PIN(Aic1) PIN(Ahc0) PIN(Ahc1)

    // ---- D-cell ownership: reg = gate, cell = 4*wv + quad, batch = col ----
    const int  cellD = 4 * wv + quad;
    const bool ewok  = (cellD < HID);
    f32x4 bias0, bias1, wx0;
    #pragma unroll
    for (int g = 0; g < 4; ++g) {
        const float s = (g == 2) ? 2.0f * LOG2E : -LOG2E;
        bias0[g] = ewok ? (b_ih0[g * HID + cellD] + b_hh0[g * HID + cellD]) * s : 0.f;
        bias1[g] = ewok ? (b_ih1[g * HID + cellD] + b_hh1[g * HID + cellD]) * s : 0.f;
        wx0[g]   = ewok ? W_ih0[g * HID + cellD] * s : 0.f;   // rank-1 x weights
    }
    // h write-back index in B-layout for (cellD, col); cellD 50/51 land in
    // the dead k=50/51 slots (zero A-weights) -> stores are unconditional.
    const int wi = (cellD >> 5) * 512 + (((cellD & 31) >> 3) * 16 + col) * 8 + (cellD & 7);

    float ct0 = 0.f, ct1 = 0.f;           // c * 2*log2e, both layers
    __syncthreads();

    // ---- prologue u=0: layer-0 only, h0^0 = 0 => gates = wx0*x_0 + bias0
    {
        const float xr = xs[xcol];
        f32x4 a;
        #pragma unroll
        for (int g = 0; g < 4; ++g) a[g] = __builtin_fmaf(wx0[g], xr, bias0[g]);
        const float h = cell_update(a, ct0);
        H0[1][wi] = (_Float16)h;          // h0^1
        __syncthreads();
    }

    // ---- main loop u=1..TT-1: both layers, branch-free ----
    #pragma unroll 2
    for (int u = 1; u < TT; ++u) {
        const int pu = u & 1, pn = pu ^ 1;

        const half8 b0c0 = *(const half8*)(&H0[pu][lane * 8]);
        const half8 b0c1 = *(const half8*)(&H0[pu][512 + lane * 8]);
        const half8 b1c0 = *(const half8*)(&H1[pn][lane * 8]);
        const half8 b1c1 = *(const half8*)(&H1[pn][512 + lane * 8]);
        const float xr   = xs[u * XST + xcol];

        // layer-0: gates0^u (x enters as rank-1 FMA into the C operand)
        f32x4 t;
        #pragma unroll
        for (int g = 0; g < 4; ++g) t[g] = __builtin_fmaf(wx0[g], xr, bias0[g]);
        f32x4 acc0 = MFMA(A0c0, b0c0, t);
        acc0 = MFMA(A0c1, b0c1, acc0);

        // layer-1: gates1 (bias fed directly as C operand, no movs)
        f32x4 acc1 = MFMA(Aic0, b0c0, bias1);   // Wi1 . h0^u
        acc1 = MFMA(Aic1, b0c1, acc1);
        acc1 = MFMA(Ahc0, b1c0, acc1);          // Wh1 . h1^{u-1}
        acc1 = MFMA(Ahc1, b1c1, acc1);

        const float h0n = cell_update(acc0, ct0);
        H0[pn][wi] = (_Float16)h0n;             // h0^{u+1}
        const float h1n = cell_update(acc1, ct1);
        H1[pu][wi] = (_Float16)h1n;             // h1^u
        __syncthreads();
    }

    // ---- epilogue u=TT (pu=0): layer-1 only -> h1^TT into hfin ----
    {
        const half8 b0c0 = *(const half8*)(&H0[0][lane * 8]);        // h0^TT
        const half8 b0c1 = *(const half8*)(&H0[0][512 + lane * 8]);
        const half8 b1c0 = *(const half8*)(&H1[1][lane * 8]);        // h1^{TT-1}
        const half8 b1c1 = *(const half8*)(&H1[1][512 + lane * 8]);
        f32x4 acc1 = MFMA(Aic0, b0c0, bias1);
        acc1 = MFMA(Aic1, b0c1, acc1);
        acc1 = MFMA(Ahc0, b1c0, acc1);
        acc1 = MFMA(Ahc1, b1c1, acc1);
        const float h1n = cell_update(acc1, ct1);
        hfin[cellD * 16 + col] = h1n;     // cells 50/51, cols 8-15 -> unused
    }
    __syncthreads();

    // ---------- FC epilogue: out[b] = fc_b + fc_w . h1^(TT)[b,:] ----------
    if (tid < NB) {
        float s = fc_b[0];
        for (int k = 0; k < HID; ++k)
            s += fc_w[k] * hfin[k * 16 + tid];
        out[b0 + tid] = s;
    }
}

extern "C" void kernel_launch(void* const* d_in, const int* in_sizes, int n_in,
                              void* d_out, int out_size, void* d_ws, size_t ws_size,
                              hipStream_t stream) {
    (void)in_sizes; (void)n_in; (void)d_ws; (void)ws_size; (void)out_size;
    const float* x     = (const float*)d_in[0];
    const float* W_ih0 = (const float*)d_in[1];
    const float* W_hh0 = (const float*)d_in[2];
    const float* b_ih0 = (const float*)d_in[3];
    const float* b_hh0 = (const float*)d_in[4];
    const float* W_ih1 = (const float*)d_in[5];
    const float* W_hh1 = (const float*)d_in[6];
    const float* b_ih1 = (const float*)d_in[7];
    const float* b_hh1 = (const float*)d_in[8];
    const float* fc_w  = (const float*)d_in[9];
    const float* fc_b  = (const float*)d_in[10];

    dim3 grid(4096 / NB);   // 512 blocks, 2 per CU -> 2 barrier domains/CU
    dim3 block(832);        // 13 waves
    lstm2_mfma_kernel<<<grid, block, 0, stream>>>(
        x, W_ih0, W_hh0, b_ih0, b_hh0,
        W_ih1, W_hh1, b_ih1, b_hh1,
        fc_w, fc_b, (float*)d_out);
}

// Round 8
// 449.377 us; speedup vs baseline: 1.5428x; 1.5428x over previous
//
#include <hip/hip_runtime.h>

// LSTMPricePredictor: B=4096, T=512, IN=1, H=50, 2 layers + FC(50->1)
// R25 = R24 resubmit (round 7 was an infra failure: "container failed
//   twice" -- no compile/correctness verdict, theory untested).
// R24 theory: R17 (best, 362us) + TRANS-PIPE DIET.
//   Post-mortem R22: 703us = 2x352 + Occupancy 39% (13 waves) => the two
//   blocks/CU were never co-resident; multi-domain route abandoned.
//   Model re-fit across R17/R18/R19/R21 (1697/1825/1898/1765 cyc/step):
//   consistent only if v_exp_f32/v_rcp_f32 occupy the trans pipe ~16cyc
//   per wave64 (GCN-width trans unit). R17 straggler SIMD: 4 waves x 14
//   trans x 16 = 896 cyc = 53% of the step. TRANS PIPE IS THE BOTTLENECK.
//   Diet: 14 -> 10 trans/thread:
//   (1) cross-layer rcp merge (4->2): R=rcp(d0*d1); range: |preact|<=8.2
//       on this data => d<=2^47, products <=2^94 < fp32 max.
//   (2) eo (both layers) via pure-VALU exp2: 2^rint(a) bit-trick *
//       Taylor-4 e^u on |u|<=0.347 (rel err 4.2e-5 << fp16 noise);
//       moves 2x16cyc to the half-idle VALU pipe; eo is off the ct chain.
//   Predict: step 1697 -> ~1450; kernel ~305-315us; VALUBusy ~60%.
//   Flat result => trans is 8cyc => pivot to VALU diet next.
// Carried from R17: x rank-1 via C-operand, bias as MFMA C-operand,
//   unconditional h stores into dead k=50/51 slots, c pre-scaled by
//   2*log2e, raw v_exp_f32; prologue/epilogue keep unmerged updates.

typedef _Float16 half8 __attribute__((ext_vector_type(8)));
typedef float    f32x4 __attribute__((ext_vector_type(4)));

#define TT    512
#define HID   50
#define NB    16         // batch rows per block
#define XST   17         // xs row stride in floats (bank-conflict-free)
#define LOG2E 1.44269504f

// Weight A-fragment: lane's 8 fp16 for K-chunk `chunk`, pre-scaled by the
// gate's exp2 factor. Row m -> gate = m&3, cell = 4*wv + (m>>2).
// W is (200 x 50): element [gate*50+cell][k]. Rows with cell >= 50 and
// k-slots >= 50 are zero (dead lanes multiply by zero).
__device__ __forceinline__ float4 make_wfrag(const float* W, int gate, int cell,
                                             int chunk, int quad, float scale) {
    half8 hv = {};
    #pragma unroll
    for (int j = 0; j < 8; ++j) {
        const int k = 32 * chunk + 8 * quad + j;
        float v = 0.0f;
        if (cell < HID && k < HID) v = W[(gate * HID + cell) * HID + k] * scale;
        hv[j] = (_Float16)v;
    }
    return __builtin_bit_cast(float4, hv);
}

// Pure-VALU exp2 (trans-pipe diet): 2^a = 2^rint(a) * e^{(a-rint(a))ln2}.
// |frac| <= 0.5 -> |u| <= 0.3466 -> Taylor-4 rel err <= u^5/120 = 4.2e-5.
// 2^n via exponent-field bit-trick (|a| <= ~12 here -> n in [-13,13], safe).
// Dead lanes: a=0 -> n=0, p=1, s=1 -> returns 1 exactly.
__device__ __forceinline__ float poly_exp2(float a) {
    const float n = __builtin_rintf(a);          // v_rndne_f32
    const float u = (a - n) * 0.69314718f;
    float p = __builtin_fmaf(u, 0.041666668f, 0.16666667f);
    p = __builtin_fmaf(u, p, 0.5f);
    p = __builtin_fmaf(u, p, 1.0f);
    p = __builtin_fmaf(u, p, 1.0f);
    const int ni = (int)n;
    const float s = __builtin_bit_cast(float, (ni + 127) << 23);
    return p * s;
}

// Original shared-rcp LSTM cell update (7 trans) -- used only in the
// prologue/epilogue (2 of 513 steps).
__device__ __forceinline__ float cell_update(const f32x4 a, float& ct) {
    const float K  = 2.0f * LOG2E;
    const float ei = __builtin_amdgcn_exp2f(a[0]);
    const float ef = __builtin_amdgcn_exp2f(a[1]);
    const float eg = __builtin_amdgcn_exp2f(a[2]);
    const float eo = __builtin_amdgcn_exp2f(a[3]);
    const float p  = (1.0f + ei) * (1.0f + eg);
    const float q  = 1.0f + ef;
    const float t1 = __builtin_fmaf(eg, K, -K);
    const float num = __builtin_fmaf(ct, p, t1 * q);
    ct = num * __builtin_amdgcn_rcpf(p * q);
    const float ec = __builtin_amdgcn_exp2f(ct);
    return (ec - 1.0f) *
        __builtin_amdgcn_rcpf((1.0f + eo) * (ec + 1.0f));
}

// Merged both-layer cell update: 10 trans (8 exp2 + 2 rcp) instead of 14.
// eo via poly_exp2 (VALU). Dead lanes: all-zero gates -> ct stays 0, h=0.
__device__ __forceinline__ void cell_update2(const f32x4 a0, const f32x4 a1,
                                             float& ct0, float& ct1,
                                             float& h0, float& h1) {
    const float K   = 2.0f * LOG2E;
    const float ei0 = __builtin_amdgcn_exp2f(a0[0]);
    const float ef0 = __builtin_amdgcn_exp2f(a0[1]);
    const float eg0 = __builtin_amdgcn_exp2f(a0[2]);
    const float ei1 = __builtin_amdgcn_exp2f(a1[0]);
    const float ef1 = __builtin_amdgcn_exp2f(a1[1]);
    const float eg1 = __builtin_amdgcn_exp2f(a1[2]);
    const float eo0 = poly_exp2(a0[3]);              // VALU, off trans pipe
    const float eo1 = poly_exp2(a1[3]);
    const float p0 = (1.0f + ei0) * (1.0f + eg0), q0 = 1.0f + ef0;
    const float p1 = (1.0f + ei1) * (1.0f + eg1), q1 = 1.0f + ef1;
    const float d0 = p0 * q0, d1 = p1 * q1;
    const float num0 = __builtin_fmaf(ct0, p0, __builtin_fmaf(eg0, K, -K) * q0);
    const float num1 = __builtin_fmaf(ct1, p1, __builtin_fmaf(eg1, K, -K) * q1);
    const float R  = __builtin_amdgcn_rcpf(d0 * d1); // merged rcp #1
    ct0 = num0 * (d1 * R);                           // = num0/d0
    ct1 = num1 * (d0 * R);
    const float ec0 = __builtin_amdgcn_exp2f(ct0);
    const float ec1 = __builtin_amdgcn_exp2f(ct1);
    const float e0 = (1.0f + eo0) * (ec0 + 1.0f);
    const float e1 = (1.0f + eo1) * (ec1 + 1.0f);
    const float R2 = __builtin_amdgcn_rcpf(e0 * e1); // merged rcp #2
    h0 = (ec0 - 1.0f) * (e1 * R2);                   // sig(o0)*tanh(c0)
    h1 = (ec1 - 1.0f) * (e0 * R2);
}

#define PIN(f) asm volatile("" : "+v"(f.x), "+v"(f.y), "+v"(f.z), "+v"(f.w));
#define MFMA(af, b, c) __builtin_amdgcn_mfma_f32_16x16x32_f16(__builtin_bit_cast(half8, (af)), (b), (c), 0, 0, 0)

extern "C" __global__ __launch_bounds__(832, 4)
void lstm2_mfma_kernel(const float* __restrict__ x,
                       const float* __restrict__ W_ih0, const float* __restrict__ W_hh0,
                       const float* __restrict__ b_ih0, const float* __restrict__ b_hh0,
                       const float* __restrict__ W_ih1, const float* __restrict__ W_hh1,
                       const float* __restrict__ b_ih1, const float* __restrict__ b_hh1,
                       const float* __restrict__ fc_w, const float* __restrict__ fc_b,
                       float* __restrict__ out)
{
    // h-state in B-fragment layout: element (k, n) at (k>>5)*512 +
    // (((k&31)>>3)*16 + n)*8 + (k&7). k<50 = h; k=50/51 slots are dead
    // (zero A-weights) and absorb the cellD=50/51 stores (h=0 anyway).
    __shared__ _Float16 H0[2][1024];
    __shared__ _Float16 H1[2][1024];
    __shared__ float    xs[TT * XST];     // x staged fp32, [u*XST + col]
    __shared__ float    hfin[52 * NB];    // fp32 h1^(TT) for the FC epilogue

    const int tid  = threadIdx.x;
    const int lane = tid & 63;
    const int wv   = tid >> 6;            // wave 0..12 = gate-row tile
    const int b0   = blockIdx.x * NB;

    for (int i = tid; i < 1024; i += 832) {
        H0[0][i] = (_Float16)0.f; H0[1][i] = (_Float16)0.f;
        H1[0][i] = (_Float16)0.f; H1[1][i] = (_Float16)0.f;
    }
    // One-shot x stage: coalesced global read, stride-17 LDS write.
    for (int i = tid; i < NB * TT; i += 832) {
        const int row = i >> 9;           // batch row 0..15
        const int uu  = i & (TT - 1);     // timestep
        xs[uu * XST + row] = x[(size_t)(b0 + row) * TT + uu];
    }

    const int quad = lane >> 4;
    const int col  = lane & 15;           // batch column
    const int mrow = lane & 15;           // A-row within tile
    const int gateA = mrow & 3;
    const int cellA = 4 * wv + (mrow >> 2);
    const float scA = (gateA == 2) ? 2.0f * LOG2E : -LOG2E;

    // ---- A-fragments (weights, exp2-prescaled), loaded once, pinned ----
    float4 A0c0 = make_wfrag(W_hh0, gateA, cellA, 0, quad, scA);
    float4 A0c1 = make_wfrag(W_hh0, gateA, cellA, 1, quad, scA);
    float4 Aic0 = make_wfrag(W_ih1, gateA, cellA, 0, quad, scA);
    float4 Aic1 = make_wfrag(W_ih1, gateA, cellA, 1, quad, scA);
    float4 Ahc0 = make_wfrag(W_hh1, gateA, cellA, 0, quad, scA);
    float4 Ahc1 = make_wfrag(W_hh1, gateA, cellA, 1, quad, scA);
    PIN(A0c0) PIN(A0c1) PIN(Aic0) PIN(Aic1) PIN(Ahc0) PIN(Ahc1)

    // ---- D-cell ownership: reg = gate, cell = 4*wv + quad, batch = col ----
    const int  cellD = 4 * wv + quad;
    const bool ewok  = (cellD < HID);
    f32x4 bias0, bias1, wx0;
    #pragma unroll
    for (int g = 0; g < 4; ++g) {
        const float s = (g == 2) ? 2.0f * LOG2E : -LOG2E;
        bias0[g] = ewok ? (b_ih0[g * HID + cellD] + b_hh0[g * HID + cellD]) * s : 0.f;
        bias1[g] = ewok ? (b_ih1[g * HID + cellD] + b_hh1[g * HID + cellD]) * s : 0.f;
        wx0[g]   = ewok ? W_ih0[g * HID + cellD] * s : 0.f;   // rank-1 x weights
    }
    // h write-back index in B-layout for (cellD, col); cellD 50/51 land in
    // the dead k=50/51 slots (zero A-weights) -> stores are unconditional.
    const int wi = (cellD >> 5) * 512 + (((cellD & 31) >> 3) * 16 + col) * 8 + (cellD & 7);

    float ct0 = 0.f, ct1 = 0.f;           // c * 2*log2e, both layers
    __syncthreads();

    // ---- prologue u=0: layer-0 only, h0^0 = 0 => gates = wx0*x_0 + bias0
    {
        const float xr = xs[col];
        f32x4 a;
        #pragma unroll
        for (int g = 0; g < 4; ++g) a[g] = __builtin_fmaf(wx0[g], xr, bias0[g]);
        const float h = cell_update(a, ct0);
        H0[1][wi] = (_Float16)h;          // h0^1
        __syncthreads();
    }

    // ---- main loop u=1..TT-1: both layers, branch-free ----
    #pragma unroll 2
    for (int u = 1; u < TT; ++u) {
        const int pu = u & 1, pn = pu ^ 1;

        const half8 b0c0 = *(const half8*)(&H0[pu][lane * 8]);
        const half8 b0c1 = *(const half8*)(&H0[pu][512 + lane * 8]);
        const half8 b1c0 = *(const half8*)(&H1[pn][lane * 8]);
        const half8 b1c1 = *(const half8*)(&H1[pn][512 + lane * 8]);
        const float xr   = xs[u * XST + col];

        // layer-0: gates0^u (x enters as rank-1 FMA into the C operand)
        f32x4 t;
        #pragma unroll
        for (int g = 0; g < 4; ++g) t[g] = __builtin_fmaf(wx0[g], xr, bias0[g]);
        f32x4 acc0 = MFMA(A0c0, b0c0, t);
        acc0 = MFMA(A0c1, b0c1, acc0);

        // layer-1: gates1 (bias fed directly as C operand, no movs)
        f32x4 acc1 = MFMA(Aic0, b0c0, bias1);   // Wi1 . h0^u
        acc1 = MFMA(Aic1, b0c1, acc1);
        acc1 = MFMA(Ahc0, b1c0, acc1);          // Wh1 . h1^{u-1}
        acc1 = MFMA(Ahc1, b1c1, acc1);

        float h0n, h1n;
        cell_update2(acc0, acc1, ct0, ct1, h0n, h1n);
        H0[pn][wi] = (_Float16)h0n;             // h0^{u+1}
        H1[pu][wi] = (_Float16)h1n;             // h1^u
        __syncthreads();
    }

    // ---- epilogue u=TT (pu=0): layer-1 only -> h1^TT into hfin ----
    {
        const half8 b0c0 = *(const half8*)(&H0[0][lane * 8]);        // h0^TT
        const half8 b0c1 = *(const half8*)(&H0[0][512 + lane * 8]);
        const half8 b1c0 = *(const half8*)(&H1[1][lane * 8]);        // h1^{TT-1}
        const half8 b1c1 = *(const half8*)(&H1[1][512 + lane * 8]);
        f32x4 acc1 = MFMA(Aic0, b0c0, bias1);
        acc1 = MFMA(Aic1, b0c1, acc1);
        acc1 = MFMA(Ahc0, b1c0, acc1);
        acc1 = MFMA(Ahc1, b1c1, acc1);
        const float h1n = cell_update(acc1, ct1);
        hfin[cellD * NB + col] = h1n;     // cells 50/51 -> unused slots
    }
    __syncthreads();

    // ---------- FC epilogue: out[b] = fc_b + fc_w . h1^(TT)[b,:] ----------
    if (tid < NB) {
        float s = fc_b[0];
        for (int k = 0; k < HID; ++k)
            s += fc_w[k] * hfin[k * NB + tid];
        out[b0 + tid] = s;
    }
}

extern "C" void kernel_launch(void* const* d_in, const int* in_sizes, int n_in,
                              void* d_out, int out_size, void* d_ws, size_t ws_size,
                              hipStream_t stream) {
    (void)in_sizes; (void)n_in; (void)d_ws; (void)ws_size; (void)out_size;
    const float* x     = (const float*)d_in[0];
    const float* W_ih0 = (const float*)d_in[1];
    const float* W_hh0 = (const float*)d_in[2];
    const float* b_ih0 = (const float*)d_in[3];
    const float* b_hh0 = (const float*)d_in[4];
    const float* W_ih1 = (const float*)d_in[5];
    const float* W_hh1 = (const float*)d_in[6];
    const float* b_ih1 = (const float*)d_in[7];
    const float* b_hh1 = (const float*)d_in[8];
    const float* fc_w  = (const float*)d_in[9];
    const float* fc_b  = (const float*)d_in[10];

    dim3 grid(4096 / NB);   // 256 blocks, 1 per CU
    dim3 block(832);        // 13 waves
    lstm2_mfma_kernel<<<grid, block, 0, stream>>>(
        x, W_ih0, W_hh0, b_ih0, b_hh0,
        W_ih1, W_hh1, b_ih1, b_hh1,
        fc_w, fc_b, (float*)d_out);
}

// Round 9
// 397.364 us; speedup vs baseline: 1.7447x; 1.1309x over previous
//
#include <hip/hip_runtime.h>

// LSTMPricePredictor: B=4096, T=512, IN=1, H=50, 2 layers + FC(50->1)
// R26 = R17 (best, 362us) + SAFE subset of the trans/VALU diet.
//   Post-mortem R25 (430us, regression): poly_exp2 ~22 VALU-busy cyc vs
//   v_exp_f32 ~8 -> "separate trans pipe @16cyc" model FALSIFIED; trans
//   ops are VALU-issue citizens at ~8cyc/wave64. R25 also coupled the two
//   ct chains via merged ct-rcp (untested in isolation). R26 keeps ALL
//   hardware trans and applies only:
//   (1) h-path rcp merge (4->3 rcp/thread-step): R2=rcp(e0*e1); does NOT
//       touch ct recurrence chains; e0,e1<=2^57, product < fp32 max;
//       dead lanes h=0 exactly.
//   (2) packed-f32 EW arithmetic: layer0/layer1 in float2 lanes so the
//       ~14 muls/fmas around the scalar trans emit v_pk_*_f32.
//   (3) vectorized bias-FMA for the MFMA C-operand.
//   Predict: 362 -> ~340-352us; VALUBusy ~44-46%. Flat => R17 structure
//   is the floor.
// Carried from R17: x rank-1 via C-operand, bias as MFMA C-operand,
//   unconditional h stores into dead k=50/51 slots, c pre-scaled by
//   2*log2e, raw v_exp_f32; prologue/epilogue keep unmerged updates.

typedef _Float16 half8 __attribute__((ext_vector_type(8)));
typedef float    f32x4 __attribute__((ext_vector_type(4)));
typedef float    f32x2 __attribute__((ext_vector_type(2)));

#define TT    512
#define HID   50
#define NB    16         // batch rows per block
#define XST   17         // xs row stride in floats (bank-conflict-free)
#define LOG2E 1.44269504f

// Weight A-fragment: lane's 8 fp16 for K-chunk `chunk`, pre-scaled by the
// gate's exp2 factor. Row m -> gate = m&3, cell = 4*wv + (m>>2).
// W is (200 x 50): element [gate*50+cell][k]. Rows with cell >= 50 and
// k-slots >= 50 are zero (dead lanes multiply by zero).
__device__ __forceinline__ float4 make_wfrag(const float* W, int gate, int cell,
                                             int chunk, int quad, float scale) {
    half8 hv = {};
    #pragma unroll
    for (int j = 0; j < 8; ++j) {
        const int k = 32 * chunk + 8 * quad + j;
        float v = 0.0f;
        if (cell < HID && k < HID) v = W[(gate * HID + cell) * HID + k] * scale;
        hv[j] = (_Float16)v;
    }
    return __builtin_bit_cast(float4, hv);
}

// Original shared-rcp LSTM cell update (7 trans) -- used only in the
// prologue/epilogue (2 of 513 steps).
__device__ __forceinline__ float cell_update(const f32x4 a, float& ct) {
    const float K  = 2.0f * LOG2E;
    const float ei = __builtin_amdgcn_exp2f(a[0]);
    const float ef = __builtin_amdgcn_exp2f(a[1]);
    const float eg = __builtin_amdgcn_exp2f(a[2]);
    const float eo = __builtin_amdgcn_exp2f(a[3]);
    const float p  = (1.0f + ei) * (1.0f + eg);
    const float q  = 1.0f + ef;
    const float t1 = __builtin_fmaf(eg, K, -K);
    const float num = __builtin_fmaf(ct, p, t1 * q);
    ct = num * __builtin_amdgcn_rcpf(p * q);
    const float ec = __builtin_amdgcn_exp2f(ct);
    return (ec - 1.0f) *
        __builtin_amdgcn_rcpf((1.0f + eo) * (ec + 1.0f));
}

// Both-layer cell update, SAFE diet: 13 trans (10 hw exp2 + 2 ct-rcp +
// 1 merged h-rcp). ct chains stay independent (unlike R25). Non-trans
// arithmetic packed as float2 (layer0 in .x, layer1 in .y) -> v_pk_*_f32.
// Dead lanes: all-zero gates -> ct stays 0, h = 0 exactly.
__device__ __forceinline__ void cell_update2(const f32x4 a0, const f32x4 a1,
                                             float& ct0, float& ct1,
                                             float& h0, float& h1) {
    const float K = 2.0f * LOG2E;
    // scalar hardware trans (10 exp2)
    const float ei0 = __builtin_amdgcn_exp2f(a0[0]);
    const float ef0 = __builtin_amdgcn_exp2f(a0[1]);
    const float eg0 = __builtin_amdgcn_exp2f(a0[2]);
    const float eo0 = __builtin_amdgcn_exp2f(a0[3]);
    const float ei1 = __builtin_amdgcn_exp2f(a1[0]);
    const float ef1 = __builtin_amdgcn_exp2f(a1[1]);
    const float eg1 = __builtin_amdgcn_exp2f(a1[2]);
    const float eo1 = __builtin_amdgcn_exp2f(a1[3]);
    // packed arithmetic around them
    const f32x2 ei = {ei0, ei1}, ef = {ef0, ef1};
    const f32x2 eg = {eg0, eg1}, ct = {ct0, ct1};
    const f32x2 one = {1.0f, 1.0f};
    const f32x2 p  = (one + ei) * (one + eg);
    const f32x2 q  = one + ef;
    const f32x2 Kv = {K, K};
    const f32x2 t1 = eg * Kv - Kv;                   // K*(eg-1), pk_fma
    const f32x2 num = ct * p + t1 * q;               // pk_fma + pk_mul
    const f32x2 d  = p * q;
    // two INDEPENDENT ct rcps (chains uncoupled across layers)
    const float r0 = __builtin_amdgcn_rcpf(d.x);
    const float r1 = __builtin_amdgcn_rcpf(d.y);
    ct0 = num.x * r0;                                // K*c'
    ct1 = num.y * r1;
    const float ec0 = __builtin_amdgcn_exp2f(ct0);   // e^{2c'}
    const float ec1 = __builtin_amdgcn_exp2f(ct1);
    // merged h-path rcp (off the recurrence chains)
    const float e0 = (1.0f + eo0) * (ec0 + 1.0f);
    const float e1 = (1.0f + eo1) * (ec1 + 1.0f);
    const float R2 = __builtin_amdgcn_rcpf(e0 * e1);
    h0 = (ec0 - 1.0f) * (e1 * R2);                   // sig(o0)*tanh(c0)
    h1 = (ec1 - 1.0f) * (e0 * R2);
}

#define PIN(f) asm volatile("" : "+v"(f.x), "+v"(f.y), "+v"(f.z), "+v"(f.w));
#define MFMA(af, b, c) __builtin_amdgcn_mfma_f32_16x16x32_f16(__builtin_bit_cast(half8, (af)), (b), (c), 0, 0, 0)

extern "C" __global__ __launch_bounds__(832, 4)
void lstm2_mfma_kernel(const float* __restrict__ x,
                       const float* __restrict__ W_ih0, const float* __restrict__ W_hh0,
                       const float* __restrict__ b_ih0, const float* __restrict__ b_hh0,
                       const float* __restrict__ W_ih1, const float* __restrict__ W_hh1,
                       const float* __restrict__ b_ih1, const float* __restrict__ b_hh1,
                       const float* __restrict__ fc_w, const float* __restrict__ fc_b,
                       float* __restrict__ out)
{
    // h-state in B-fragment layout: element (k, n) at (k>>5)*512 +
    // (((k&31)>>3)*16 + n)*8 + (k&7). k<50 = h; k=50/51 slots are dead
    // (zero A-weights) and absorb the cellD=50/51 stores (h=0 anyway).
    __shared__ _Float16 H0[2][1024];
    __shared__ _Float16 H1[2][1024];
    __shared__ float    xs[TT * XST];     // x staged fp32, [u*XST + col]
    __shared__ float    hfin[52 * NB];    // fp32 h1^(TT) for the FC epilogue

    const int tid  = threadIdx.x;
    const int lane = tid & 63;
    const int wv   = tid >> 6;            // wave 0..12 = gate-row tile
    const int b0   = blockIdx.x * NB;

    for (int i = tid; i < 1024; i += 832) {
        H0[0][i] = (_Float16)0.f; H0[1][i] = (_Float16)0.f;
        H1[0][i] = (_Float16)0.f; H1[1][i] = (_Float16)0.f;
    }
    // One-shot x stage: coalesced global read, stride-17 LDS write.
    for (int i = tid; i < NB * TT; i += 832) {
        const int row = i >> 9;           // batch row 0..15
        const int uu  = i & (TT - 1);     // timestep
        xs[uu * XST + row] = x[(size_t)(b0 + row) * TT + uu];
    }

    const int quad = lane >> 4;
    const int col  = lane & 15;           // batch column
    const int mrow = lane & 15;           // A-row within tile
    const int gateA = mrow & 3;
    const int cellA = 4 * wv + (mrow >> 2);
    const float scA = (gateA == 2) ? 2.0f * LOG2E : -LOG2E;

    // ---- A-fragments (weights, exp2-prescaled), loaded once, pinned ----
    float4 A0c0 = make_wfrag(W_hh0, gateA, cellA, 0, quad, scA);
    float4 A0c1 = make_wfrag(W_hh0, gateA, cellA, 1, quad, scA);
    float4 Aic0 = make_wfrag(W_ih1, gateA, cellA, 0, quad, scA);
    float4 Aic1 = make_wfrag(W_ih1, gateA, cellA, 1, quad, scA);
    float4 Ahc0 = make_wfrag(W_hh1, gateA, cellA, 0, quad, scA);
    float4 Ahc1 = make_wfrag(W_hh1, gateA, cellA, 1, quad, scA);
    PIN(A0c0) PIN(A0c1) PIN(Aic0) PIN(Aic1) PIN(Ahc0) PIN(Ahc1)

    // ---- D-cell ownership: reg = gate, cell = 4*wv + quad, batch = col ----
    const int  cellD = 4 * wv + quad;
    const bool ewok  = (cellD < HID);
    f32x4 bias0, bias1, wx0;
    #pragma unroll
    for (int g = 0; g < 4; ++g) {
        const float s = (g == 2) ? 2.0f * LOG2E : -LOG2E;
        bias0[g] = ewok ? (b_ih0[g * HID + cellD] + b_hh0[g * HID + cellD]) * s : 0.f;
        bias1[g] = ewok ? (b_ih1[g * HID + cellD] + b_hh1[g * HID + cellD]) * s : 0.f;
        wx0[g]   = ewok ? W_ih0[g * HID + cellD] * s : 0.f;   // rank-1 x weights
    }
    // h write-back index in B-layout for (cellD, col); cellD 50/51 land in
    // the dead k=50/51 slots (zero A-weights) -> stores are unconditional.
    const int wi = (cellD >> 5) * 512 + (((cellD & 31) >> 3) * 16 + col) * 8 + (cellD & 7);

    float ct0 = 0.f, ct1 = 0.f;           // c * 2*log2e, both layers
    __syncthreads();

    // ---- prologue u=0: layer-0 only, h0^0 = 0 => gates = wx0*x_0 + bias0
    {
        const float xr = xs[col];
        f32x4 a;
        #pragma unroll
        for (int g = 0; g < 4; ++g) a[g] = __builtin_fmaf(wx0[g], xr, bias0[g]);
        const float h = cell_update(a, ct0);
        H0[1][wi] = (_Float16)h;          // h0^1
        __syncthreads();
    }

    // ---- main loop u=1..TT-1: both layers, branch-free ----
    #pragma unroll 2
    for (int u = 1; u < TT; ++u) {
        const int pu = u & 1, pn = pu ^ 1;

        const half8 b0c0 = *(const half8*)(&H0[pu][lane * 8]);
        const half8 b0c1 = *(const half8*)(&H0[pu][512 + lane * 8]);
        const half8 b1c0 = *(const half8*)(&H1[pn][lane * 8]);
        const half8 b1c1 = *(const half8*)(&H1[pn][512 + lane * 8]);
        const float xr   = xs[u * XST + col];

        // layer-0: gates0^u (x enters as rank-1 FMA into the C operand);
        // vector expression -> v_pk_fma_f32 candidates
        const f32x4 xrv = {xr, xr, xr, xr};
        const f32x4 t = wx0 * xrv + bias0;
        f32x4 acc0 = MFMA(A0c0, b0c0, t);
        acc0 = MFMA(A0c1, b0c1, acc0);

        // layer-1: gates1 (bias fed directly as C operand, no movs)
        f32x4 acc1 = MFMA(Aic0, b0c0, bias1);   // Wi1 . h0^u
        acc1 = MFMA(Aic1, b0c1, acc1);
        acc1 = MFMA(Ahc0, b1c0, acc1);          // Wh1 . h1^{u-1}
        acc1 = MFMA(Ahc1, b1c1, acc1);

        float h0n, h1n;
        cell_update2(acc0, acc1, ct0, ct1, h0n, h1n);
        H0[pn][wi] = (_Float16)h0n;             // h0^{u+1}
        H1[pu][wi] = (_Float16)h1n;             // h1^u
        __syncthreads();
    }

    // ---- epilogue u=TT (pu=0): layer-1 only -> h1^TT into hfin ----
    {
        const half8 b0c0 = *(const half8*)(&H0[0][lane * 8]);        // h0^TT
        const half8 b0c1 = *(const half8*)(&H0[0][512 + lane * 8]);
        const half8 b1c0 = *(const half8*)(&H1[1][lane * 8]);        // h1^{TT-1}
        const half8 b1c1 = *(const half8*)(&H1[1][512 + lane * 8]);
        f32x4 acc1 = MFMA(Aic0, b0c0, bias1);
        acc1 = MFMA(Aic1, b0c1, acc1);
        acc1 = MFMA(Ahc0, b1c0, acc1);
        acc1 = MFMA(Ahc1, b1c1, acc1);
        const float h1n = cell_update(acc1, ct1);
        hfin[cellD * NB + col] = h1n;     // cells 50/51 -> unused slots
    }
    __syncthreads();

    // ---------- FC epilogue: out[b] = fc_b + fc_w . h1^(TT)[b,:] ----------
    if (tid < NB) {
        float s = fc_b[0];
        for (int k = 0; k < HID; ++k)
            s += fc_w[k] * hfin[k * NB + tid];
        out[b0 + tid] = s;
    }
}

extern "C" void kernel_launch(void* const* d_in, const int* in_sizes, int n_in,
                              void* d_out, int out_size, void* d_ws, size_t ws_size,
                              hipStream_t stream) {
    (void)in_sizes; (void)n_in; (void)d_ws; (void)ws_size; (void)out_size;
    const float* x     = (const float*)d_in[0];
    const float* W_ih0 = (const float*)d_in[1];
    const float* W_hh0 = (const float*)d_in[2];
    const float* b_ih0 = (const float*)d_in[3];
    const float* b_hh0 = (const float*)d_in[4];
    const float* W_ih1 = (const float*)d_in[5];
    const float* W_hh1 = (const float*)d_in[6];
    const float* b_ih1 = (const float*)d_in[7];
    const float* b_hh1 = (const float*)d_in[8];
    const float* fc_w  = (const float*)d_in[9];
    const float* fc_b  = (const float*)d_in[10];

    dim3 grid(4096 / NB);   // 256 blocks, 1 per CU
    dim3 block(832);        // 13 waves
    lstm2_mfma_kernel<<<grid, block, 0, stream>>>(
        x, W_ih0, W_hh0, b_ih0, b_hh0,
        W_ih1, W_hh1, b_ih1, b_hh1,
        fc_w, fc_b, (float*)d_out);
}

// Round 10
// 385.752 us; speedup vs baseline: 1.7972x; 1.0301x over previous
//
#include <hip/hip_runtime.h>

// LSTMPricePredictor: B=4096, T=512, IN=1, H=50, 2 layers + FC(50->1)
// R27 = R17 VERBATIM REVERT -- session best (362us kernel, 386.9 dur_us).
//   Final post-mortem: eight theories after R17 all regressed or flat:
//   R18 fewer-LDS-reads -7%, R19 K-split 2-barrier -12%, R21 micro-bundle
//   -4%, R22 dual barrier domains -94% (blocks never co-resident), R25
//   poly-exp2 trans diet -19% (trans ops are cheap VALU citizens ~8cyc),
//   R26 rcp-merge+packed-f32 -2% (EW issue count not binding).
//   Conclusion: kernel is RECURRENCE-LATENCY/SYNC-BOUND: 512 serial
//   timesteps x barrier-locksteped {ds_read -> MFMA -> EW -> write ->
//   barrier}, every op on the LSTM's sequential dependence. Not HBM
//   (0.17%), not MFMA (19%), not VALU-throughput (48%, and reducing VALU
//   work regressed). This structure is the practical floor.
// R17 = R16 + {x rank-1 via LDS stage, branch-peeled main loop, bias as
//   MFMA C-operand, unconditional h stores into dead k=50/51 slots,
//   2-rcp cell_update with c pre-scaled by 2*log2e, raw v_exp_f32}.

typedef _Float16 half8 __attribute__((ext_vector_type(8)));
typedef float    f32x4 __attribute__((ext_vector_type(4)));

#define TT    512
#define HID   50
#define NB    16         // batch rows per block
#define XST   17         // xs row stride in floats (bank-conflict-free)
#define LOG2E 1.44269504f

// Weight A-fragment: lane's 8 fp16 for K-chunk `chunk`, pre-scaled by the
// gate's exp2 factor. Row m -> gate = m&3, cell = 4*wv + (m>>2).
// W is (200 x 50): element [gate*50+cell][k]. k>=50 rows are zero (the
// k=50/51 B-slots receive dead-lane junk and must multiply by zero).
__device__ __forceinline__ float4 make_wfrag(const float* W, int gate, int cell,
                                             int chunk, int quad, float scale) {
    half8 hv = {};
    #pragma unroll
    for (int j = 0; j < 8; ++j) {
        const int k = 32 * chunk + 8 * quad + j;
        float v = 0.0f;
        if (cell < HID && k < HID) v = W[(gate * HID + cell) * HID + k] * scale;
        hv[j] = (_Float16)v;
    }
    return __builtin_bit_cast(float4, hv);
}

// Shared-rcp LSTM cell update on pre-scaled gates, RAW hardware exp2.
//   a0 = -i*log2e, a1 = -f*log2e, a2 = 2g*log2e, a3 = -o*log2e.
// ct = c * 2*log2e is carried across steps (mul off the exp2 chain).
// Common denominator: c' = c*sig(f) + sig(i)*tanh(g)
//   = [ct*p + K(eg-1)*q] / (p*q) / K,  p=(1+ei)(1+eg), q=(1+ef), K=2log2e.
// Worst-case p*q <= 2^82 (gate |preact| <= ~14.2) -- no overflow.
__device__ __forceinline__ float cell_update(const f32x4 a, float& ct) {
    const float K  = 2.0f * LOG2E;
    const float ei = __builtin_amdgcn_exp2f(a[0]);   // e^{-i}
    const float ef = __builtin_amdgcn_exp2f(a[1]);   // e^{-f}
    const float eg = __builtin_amdgcn_exp2f(a[2]);   // e^{2g}
    const float eo = __builtin_amdgcn_exp2f(a[3]);   // e^{-o}
    const float p  = (1.0f + ei) * (1.0f + eg);
    const float q  = 1.0f + ef;
    const float t1 = __builtin_fmaf(eg, K, -K);                  // K*(eg-1)
    const float num = __builtin_fmaf(ct, p, t1 * q);
    ct = num * __builtin_amdgcn_rcpf(p * q);                     // K*c'
    const float ec = __builtin_amdgcn_exp2f(ct);                 // e^{2c'}
    return (ec - 1.0f) *
        __builtin_amdgcn_rcpf((1.0f + eo) * (ec + 1.0f));        // sig(o)*tanh(c')
}

#define PIN(f) asm volatile("" : "+v"(f.x), "+v"(f.y), "+v"(f.z), "+v"(f.w));
#define MFMA(af, b, c) __builtin_amdgcn_mfma_f32_16x16x32_f16(__builtin_bit_cast(half8, (af)), (b), (c), 0, 0, 0)

extern "C" __global__ __launch_bounds__(832, 4)
void lstm2_mfma_kernel(const float* __restrict__ x,
                       const float* __restrict__ W_ih0, const float* __restrict__ W_hh0,
                       const float* __restrict__ b_ih0, const float* __restrict__ b_hh0,
                       const float* __restrict__ W_ih1, const float* __restrict__ W_hh1,
                       const float* __restrict__ b_ih1, const float* __restrict__ b_hh1,
                       const float* __restrict__ fc_w, const float* __restrict__ fc_b,
                       float* __restrict__ out)
{
    // h-state in B-fragment layout: element (k, n) at (k>>5)*512 +
    // (((k&31)>>3)*16 + n)*8 + (k&7). k<50 = h; k=50/51 slots are dead
    // (zero A-weights) and absorb the cellD=50/51 junk stores.
    __shared__ _Float16 H0[2][1024];
    __shared__ _Float16 H1[2][1024];
    __shared__ float    xs[TT * XST];     // x staged fp32, [u*XST + col]
    __shared__ float    hfin[52 * NB];    // fp32 h1^(TT) for the FC epilogue

    const int tid  = threadIdx.x;
    const int lane = tid & 63;
    const int wv   = tid >> 6;            // wave 0..12 = gate-row tile
    const int b0   = blockIdx.x * NB;

    for (int i = tid; i < 1024; i += 832) {
        H0[0][i] = (_Float16)0.f; H0[1][i] = (_Float16)0.f;
        H1[0][i] = (_Float16)0.f; H1[1][i] = (_Float16)0.f;
    }
    // One-shot x stage: coalesced global read, stride-17 LDS write.
    for (int i = tid; i < NB * TT; i += 832) {
        const int row = i >> 9;           // batch row 0..15
        const int uu  = i & (TT - 1);     // timestep
        xs[uu * XST + row] = x[(size_t)(b0 + row) * TT + uu];
    }

    const int quad = lane >> 4;
    const int col  = lane & 15;           // batch column

    // ---- A-fragments (weights, exp2-prescaled), loaded once, pinned ----
    const int mrow  = lane & 15;          // A-row within tile
    const int gateA = mrow & 3;
    const int cellA = 4 * wv + (mrow >> 2);
    const float scA = (gateA == 2) ? 2.0f * LOG2E : -LOG2E;
    float4 A0c0 = make_wfrag(W_hh0, gateA, cellA, 0, quad, scA);
    float4 A0c1 = make_wfrag(W_hh0, gateA, cellA, 1, quad, scA);
    float4 Aic0 = make_wfrag(W_ih1, gateA, cellA, 0, quad, scA);
    float4 Aic1 = make_wfrag(W_ih1, gateA, cellA, 1, quad, scA);
    float4 Ahc0 = make_wfrag(W_hh1, gateA, cellA, 0, quad, scA);
    float4 Ahc1 = make_wfrag(W_hh1, gateA, cellA, 1, quad, scA);
    PIN(A0c0) PIN(A0c1) PIN(Aic0) PIN(Aic1) PIN(Ahc0) PIN(Ahc1)

    // ---- D-cell ownership: reg = gate, cell = 4*wv + quad, batch = col ----
    const int  cellD = 4 * wv + quad;
    const bool ewok  = (cellD < HID);
    f32x4 bias0, bias1, wx0;
    #pragma unroll
    for (int g = 0; g < 4; ++g) {
        const float s = (g == 2) ? 2.0f * LOG2E : -LOG2E;
        bias0[g] = ewok ? (b_ih0[g * HID + cellD] + b_hh0[g * HID + cellD]) * s : 0.f;
        bias1[g] = ewok ? (b_ih1[g * HID + cellD] + b_hh1[g * HID + cellD]) * s : 0.f;
        wx0[g]   = ewok ? W_ih0[g * HID + cellD] * s : 0.f;   // rank-1 x weights
    }
    // h write-back index in B-layout for (cellD, col); cellD=50/51 land in
    // the dead k=50/51 slots (zero A-weights) -> stores are unconditional.
    const int wi = (cellD >> 5) * 512 + (((cellD & 31) >> 3) * 16 + col) * 8 + (cellD & 7);

    float ct0 = 0.f, ct1 = 0.f;           // c * 2*log2e, both layers
    __syncthreads();

    // ---- prologue u=0: layer-0 only, h0^0 = 0 => gates = wx0*x_0 + bias0
    {
        const float xr = xs[col];
        f32x4 acc;
        #pragma unroll
        for (int g = 0; g < 4; ++g) acc[g] = __builtin_fmaf(wx0[g], xr, bias0[g]);
        const float h = cell_update(acc, ct0);
        H0[1][wi] = (_Float16)h;          // h0^1
        __syncthreads();
    }

    // ---- main loop u=1..TT-1: both layers, branch-free ----
    #pragma unroll 2
    for (int u = 1; u < TT; ++u) {
        const int pu = u & 1, pn = pu ^ 1;

        const half8 b0c0 = *(const half8*)(&H0[pu][lane * 8]);
        const half8 b0c1 = *(const half8*)(&H0[pu][512 + lane * 8]);
        const half8 b1c0 = *(const half8*)(&H1[pn][lane * 8]);
        const half8 b1c1 = *(const half8*)(&H1[pn][512 + lane * 8]);
        const float xr   = xs[u * XST + col];

        // layer-0: gates0^u (x enters as rank-1 FMA into the C operand)
        f32x4 t;
        #pragma unroll
        for (int g = 0; g < 4; ++g) t[g] = __builtin_fmaf(wx0[g], xr, bias0[g]);
        f32x4 acc0 = MFMA(A0c0, b0c0, t);
        acc0 = MFMA(A0c1, b0c1, acc0);

        // layer-1: gates1 (bias fed directly as C operand, no movs)
        f32x4 acc1 = MFMA(Aic0, b0c0, bias1);   // Wi1 . h0^u
        acc1 = MFMA(Aic1, b0c1, acc1);
        acc1 = MFMA(Ahc0, b1c0, acc1);          // Wh1 . h1^{u-1}
        acc1 = MFMA(Ahc1, b1c1, acc1);

        const float h0n = cell_update(acc0, ct0);
        H0[pn][wi] = (_Float16)h0n;             // h0^{u+1}
        const float h1n = cell_update(acc1, ct1);
        H1[pu][wi] = (_Float16)h1n;             // h1^u
        __syncthreads();
    }

    // ---- epilogue u=TT: layer-1 only -> h1^TT into hfin ----
    {
        const half8 b0c0 = *(const half8*)(&H0[0][lane * 8]);        // h0^TT
        const half8 b0c1 = *(const half8*)(&H0[0][512 + lane * 8]);
        const half8 b1c0 = *(const half8*)(&H1[1][lane * 8]);        // h1^{TT-1}
        const half8 b1c1 = *(const half8*)(&H1[1][512 + lane * 8]);
        f32x4 acc1 = MFMA(Aic0, b0c0, bias1);
        acc1 = MFMA(Aic1, b0c1, acc1);
        acc1 = MFMA(Ahc0, b1c0, acc1);
        acc1 = MFMA(Ahc1, b1c1, acc1);
        const float h1n = cell_update(acc1, ct1);
        hfin[cellD * NB + col] = h1n;           // cells 50/51 -> unused slots
    }
    __syncthreads();

    // ---------- FC epilogue: out[b] = fc_b + fc_w . h1^(TT)[b,:] ----------
    if (tid < NB) {
        float s = fc_b[0];
        for (int k = 0; k < HID; ++k)
            s += fc_w[k] * hfin[k * NB + tid];
        out[b0 + tid] = s;
    }
}

extern "C" void kernel_launch(void* const* d_in, const int* in_sizes, int n_in,
                              void* d_out, int out_size, void* d_ws, size_t ws_size,
                              hipStream_t stream) {
    (void)in_sizes; (void)n_in; (void)d_ws; (void)ws_size; (void)out_size;
    const float* x     = (const float*)d_in[0];
    const float* W_ih0 = (const float*)d_in[1];
    const float* W_hh0 = (const float*)d_in[2];
    const float* b_ih0 = (const float*)d_in[3];
    const float* b_hh0 = (const float*)d_in[4];
    const float* W_ih1 = (const float*)d_in[5];
    const float* W_hh1 = (const float*)d_in[6];
    const float* b_ih1 = (const float*)d_in[7];
    const float* b_hh1 = (const float*)d_in[8];
    const float* fc_w  = (const float*)d_in[9];
    const float* fc_b  = (const float*)d_in[10];

    dim3 grid(4096 / NB);   // 256 blocks, 1 per CU
    dim3 block(832);        // 13 waves
    lstm2_mfma_kernel<<<grid, block, 0, stream>>>(
        x, W_ih0, W_hh0, b_ih0, b_hh0,
        W_ih1, W_hh1, b_ih1, b_hh1,
        fc_w, fc_b, (float*)d_out);
}